// Round 18
// baseline (274.835 us; speedup 1.0000x reference)
//
#include <hip/hip_runtime.h>
#include <hip/hip_fp16.h>
#include <math.h>

// LSTM: B=512, T=512, D=128, H=64. out = h_T [512,64] fp32.
// Phase 1 (xg_gemm2): xg = x@W_ih^T + b via bf16-MFMA (hi/lo x), CELL-MAJOR f16.
// Phase 2 (lstm_rec16): 512 blocks x 128 thr (2 waves). Lane = cell*2 + p.
//   K-SPLIT refinement of r17: parity p owns K-half p for ALL 4 gates
//   (W still 64 f16x2 words/lane -> resident under the ~132-VGPR allocator
//   cap). h-read per lane halves to 4xds_read_b128 (64B); per-CU post-barrier
//   LDS burst halves (32->16 b128, ~190cyc). Half-dots combined via 4 DPP
//   pair-swap+adds; r17's activation/exchange tail unchanged.

#define Bsz   512
#define Tlen  512
#define Din   128
#define Hdim  64
#define NGATE 256

typedef __attribute__((ext_vector_type(8))) short short8v;
typedef __attribute__((ext_vector_type(4))) float f32x4;
typedef __attribute__((ext_vector_type(2))) _Float16 h2v;
typedef unsigned short ushort_t;
typedef unsigned int uint_t;
typedef __attribute__((ext_vector_type(4))) uint_t uint4v;

__device__ __forceinline__ unsigned short f2bf_bits(float f) {
    union { float f; unsigned u; } v; v.f = f;
    unsigned r = v.u + 0x7fff + ((v.u >> 16) & 1);   // RNE
    return (unsigned short)(r >> 16);
}
__device__ __forceinline__ float bf2f(unsigned short b) {
    union { unsigned u; float f; } v; v.u = ((unsigned)b) << 16;
    return v.f;
}
__device__ __forceinline__ uint_t pkh(float a, float b) {   // pack 2xf16 (RNE)
    return (uint_t)__half_as_ushort(__float2half(a)) |
           ((uint_t)__half_as_ushort(__float2half(b)) << 16);
}
__device__ __forceinline__ h2v as_h2(uint_t u) {
    union { uint_t u; h2v h; } v; v.u = u; return v.h;
}
__device__ __forceinline__ float f16lo(uint_t u) {
    return __half2float(__ushort_as_half((ushort_t)(u & 0xffff)));
}
__device__ __forceinline__ float f16hi(uint_t u) {
    return __half2float(__ushort_as_half((ushort_t)(u >> 16)));
}
__device__ __forceinline__ float sigmoid_f(float v) {
    return 1.0f / (1.0f + __expf(-v));
}
__device__ __forceinline__ float tanh_f(float v) {
    float a = fabsf(v);
    float e = __expf(2.0f * a);
    float r = 1.0f - 2.0f / (e + 1.0f);
    return copysignf(r, v);
}

// DPP pair swap: lane l <-> lane l^1 within each quad (quad_perm [1,0,3,2]).
__device__ __forceinline__ float pswap(float v) {
    int r = __builtin_amdgcn_update_dpp(0, __float_as_int(v), 0xB1, 0xF, 0xF, true);
    return __int_as_float(r);
}

#if defined(__has_builtin)
#if __has_builtin(__builtin_amdgcn_fdot2)
#define FDOT2(a, b, c) __builtin_amdgcn_fdot2((a), (b), (c), false)
#endif
#endif
#ifndef FDOT2
#define FDOT2(a, b, c) fmaf((float)(a)[1], (float)(b)[1], fmaf((float)(a)[0], (float)(b)[0], (c)))
#endif

#define MF(acc, a, b) acc = __builtin_amdgcn_mfma_f32_16x16x32_bf16(a, b, acc, 0, 0, 0)

// ---------------- Phase 1: xg cell-major f16 (unchanged, ~roofline) -----------
__global__ __launch_bounds__(256, 1)
void xg_gemm2(const float* __restrict__ x, const float* __restrict__ W_ih,
              const float* __restrict__ b_ih, const float* __restrict__ b_hh,
              uint_t* __restrict__ xg)
{
    __shared__ __align__(16) ushort_t sxh[2][16][136];  // x-tile hi (pad 136)
    __shared__ __align__(16) ushort_t sxl[2][16][136];  // x-tile lo

    const int tid = threadIdx.x;
    const int l = tid & 63, q = tid >> 6;
    const int jl = l & 15, s4 = l >> 4;
    const int rb = blockIdx.x & 31, tc = blockIdx.x >> 5;
    const int t0 = tc * 32;

    short8v wb[4][4];
    #pragma unroll
    for (int tt = 0; tt < 4; ++tt) {
        #pragma unroll
        for (int kt = 0; kt < 4; ++kt) {
            const float* wp = W_ih + (size_t)(tt * 64 + q * 16 + jl) * Din + kt * 32 + s4 * 8;
            f32x4 v0 = *(const f32x4*)wp;
            f32x4 v1 = *(const f32x4*)(wp + 4);
            #pragma unroll
            for (int j = 0; j < 8; ++j)
                wb[tt][kt][j] = (short)f2bf_bits((j < 4) ? v0[j] : v1[j - 4]);
        }
    }
    float bias[4];
    #pragma unroll
    for (int tt = 0; tt < 4; ++tt) {
        int g = tt * 64 + q * 16 + jl;
        bias[tt] = b_ih[g] + b_hh[g];
    }

    const int srow = tid >> 4, spart = tid & 15;
    const float* xrow = x + (size_t)(rb * 16 + srow) * Tlen * Din + spart * 8;
    f32x4 xr0 = *(const f32x4*)(xrow + (size_t)t0 * Din);
    f32x4 xr1 = *(const f32x4*)(xrow + (size_t)t0 * Din + 4);

    for (int ti = 0; ti < 32; ++ti) {
        const int t = t0 + ti, buf = ti & 1;

        short8v vh, vl;
        #pragma unroll
        for (int j = 0; j < 8; ++j) {
            float f = (j < 4) ? xr0[j] : xr1[j - 4];
            unsigned short hb = f2bf_bits(f);
            vh[j] = (short)hb;
            vl[j] = (short)f2bf_bits(f - bf2f(hb));
        }
        *(short8v*)&sxh[buf][srow][spart * 8] = vh;
        *(short8v*)&sxl[buf][srow][spart * 8] = vl;
        __syncthreads();

        if (ti + 1 < 32) {
            xr0 = *(const f32x4*)(xrow + (size_t)(t + 1) * Din);
            xr1 = *(const f32x4*)(xrow + (size_t)(t + 1) * Din + 4);
        }

        f32x4 acc0 = {0.f, 0.f, 0.f, 0.f}, acc1 = acc0, acc2 = acc0, acc3 = acc0;
        #pragma unroll
        for (int kt = 0; kt < 4; ++kt) {
            short8v ah = *(const short8v*)&sxh[buf][jl][kt * 32 + s4 * 8];
            short8v al = *(const short8v*)&sxl[buf][jl][kt * 32 + s4 * 8];
            MF(acc0, ah, wb[0][kt]); MF(acc1, ah, wb[1][kt]);
            MF(acc2, ah, wb[2][kt]); MF(acc3, ah, wb[3][kt]);
            MF(acc0, al, wb[0][kt]); MF(acc1, al, wb[1][kt]);
            MF(acc2, al, wb[2][kt]); MF(acc3, al, wb[3][kt]);
        }

        // C layout: col(gate-sub)=jl, row(batch-sub)=s4*4+r. Cell-major store.
        #pragma unroll
        for (int r = 0; r < 4; ++r) {
            const int brow = rb * 16 + s4 * 4 + r;
            uint2 st;
            st.x = pkh(acc0[r] + bias[0], acc1[r] + bias[1]);   // i, f
            st.y = pkh(acc2[r] + bias[2], acc3[r] + bias[3]);   // g, o
            *(uint2*)(xg + ((size_t)brow * Tlen + t) * 128 + (q * 16 + jl) * 2) = st;
        }
    }
}

// ---------------- Phase 2: 2-wave K-split pair-DPP recurrence -----------------
// 512 blocks x 128 thr. Wave w: cells [32w, 32w+32); lane = (c&31)*2 + p.
// Parity p owns K-half [32p, 32p+32) for ALL 4 gates (W = 64 f16x2 words).
__global__ __launch_bounds__(128) __attribute__((amdgpu_waves_per_eu(1, 1)))
void lstm_rec16(const uint_t* __restrict__ xg, const float* __restrict__ W_hh,
                float* __restrict__ out)
{
    __shared__ __align__(16) ushort_t hsh[2][Hdim];  // f16 h, double-buffered

    const int tid = threadIdx.x;
    const int l = tid & 63;
    const int w = tid >> 6;           // wave 0..1
    const int p = l & 1;              // K-half owner & gate-pair for xg
    const int j = w * 32 + (l >> 1);  // cell 0..63
    const int b = blockIdx.x;         // batch row

    // W rows for gates {i,f,g,o} of cell j, K-half p: 4 gates x 4 uint4v.
    uint4v Wg[4][4];
    #pragma unroll
    for (int tt = 0; tt < 4; ++tt) {
        const float2* wr = (const float2*)(W_hh + (size_t)(tt * Hdim + j) * Hdim + p * 32);
        #pragma unroll
        for (int qq = 0; qq < 4; ++qq) {
            #pragma unroll
            for (int cc = 0; cc < 4; ++cc) {
                float2 ww = wr[qq * 4 + cc];
                Wg[tt][qq][cc] = pkh(ww.x, ww.y);
            }
        }
    }

    if (tid < Hdim) hsh[0][tid] = 0;   // h0 = 0
    float c = 0.f, h = 0.f;
    __syncthreads();

    // cell-major xg: dword p of cell j's packet (p=0 -> {i,f}, p=1 -> {g,o})
    const uint_t* xp = xg + (size_t)b * (Tlen * 128) + j * 2 + p;

    // 4-step register batches, A/B double buffer (8 regs)
    uint_t xA[4], xB[4];
    #pragma unroll
    for (int i = 0; i < 4; ++i) xA[i] = xp[(size_t)i * 128];
    #pragma unroll
    for (int i = 0; i < 4; ++i) xB[i] = xp[(size_t)(4 + i) * 128];

#define STEP1(xv, SI) do {                                                     \
    const int buf_ = (SI) & 1;                                                 \
    /* h K-half read: 4 x ds_read_b128 (2 bcast addrs/wave, 2-way = free) */   \
    const uint4v* hp_ = (const uint4v*)&hsh[buf_][p * 32];                     \
    uint4v hq_[4];                                                             \
    _Pragma("unroll")                                                          \
    for (int i_ = 0; i_ < 4; ++i_) hq_[i_] = hp_[i_];                          \
    /* 4 half-dots (one per gate), 4 chains of 4 fdot2 each */                 \
    float d_[4];                                                               \
    _Pragma("unroll")                                                          \
    for (int tt_ = 0; tt_ < 4; ++tt_) {                                        \
        float a0 = 0.f, a1 = 0.f, a2 = 0.f, a3 = 0.f;                          \
        _Pragma("unroll")                                                      \
        for (int q_ = 0; q_ < 4; ++q_) {                                       \
            a0 = FDOT2(as_h2(hq_[q_][0]), as_h2(Wg[tt_][q_][0]), a0);          \
            a1 = FDOT2(as_h2(hq_[q_][1]), as_h2(Wg[tt_][q_][1]), a1);          \
            a2 = FDOT2(as_h2(hq_[q_][2]), as_h2(Wg[tt_][q_][2]), a2);          \
            a3 = FDOT2(as_h2(hq_[q_][3]), as_h2(Wg[tt_][q_][3]), a3);          \
        }                                                                      \
        d_[tt_] = (a0 + a1) + (a2 + a3);                                       \
    }                                                                          \
    /* combine K-halves across the pair: full dot per gate */                  \
    float fi = d_[0] + pswap(d_[0]);                                           \
    float ff = d_[1] + pswap(d_[1]);                                           \
    float fg2 = d_[2] + pswap(d_[2]);                                          \
    float fo = d_[3] + pswap(d_[3]);                                           \
    /* own 2 pre-acts: p=0 -> {i,f}; p=1 -> {g,o} (xg dword matches) */        \
    float preA = (p ? fg2 : fi) + f16lo(xv);                                   \
    float preB = (p ? fo  : ff) + f16hi(xv);                                   \
    float pxA  = p ? 2.0f * preA : preA;                                       \
    float sgA  = 1.0f / (1.0f + __expf(-pxA));                                 \
    float actA = p ? 2.0f * sgA - 1.0f : sgA;                                  \
    float actB = 1.0f / (1.0f + __expf(-preB));                                \
    /* pair exchange of activated gates via DPP (lane ^ 1) */                  \
    float oA = pswap(actA);                                                    \
    float oB = pswap(actB);                                                    \
    float iv = p ? oA   : actA;                                                \
    float fv = p ? oB   : actB;                                                \
    float gv = p ? actA : oA;                                                  \
    float ov = p ? actB : oB;                                                  \
    c = fv * c + iv * gv;                                                      \
    h = ov * tanh_f(c);                                                        \
    if (p == 0) hsh[buf_ ^ 1][j] = __half_as_ushort(__float2half(h));          \
    __syncthreads();                                                           \
} while (0)

#define STEP4(XARR) do {                                                       \
    _Pragma("unroll")                                                          \
    for (int si_ = 0; si_ < 4; ++si_) STEP1(XARR[si_], si_);                   \
} while (0)

    for (int bt = 0; bt < 128; bt += 2) {
        STEP4(xA);
        if (bt + 2 < 128) {
            const uint_t* rp = xp + (size_t)(bt + 2) * 4 * 128;
            #pragma unroll
            for (int i = 0; i < 4; ++i) xA[i] = rp[(size_t)i * 128];
        }
        STEP4(xB);
        if (bt + 3 < 128) {
            const uint_t* rp = xp + (size_t)(bt + 3) * 4 * 128;
            #pragma unroll
            for (int i = 0; i < 4; ++i) xB[i] = rp[(size_t)i * 128];
        }
    }
#undef STEP4
#undef STEP1

    if (p == 0) out[(size_t)b * Hdim + j] = h;
}

// ---------------- Fallback: round-1 fused kernel (proven correct) -------------
#define LDS_DWORDS 33920
__global__ void __launch_bounds__(256, 1)
lstm_fused(const float* __restrict__ x, const float* __restrict__ W_ih,
           const float* __restrict__ W_hh, const float* __restrict__ b_ih,
           const float* __restrict__ b_hh, float* __restrict__ out)
{
    extern __shared__ float lds[];
    float* wih   = lds;
    float* xbuf  = lds + 32768;
    float* gates = lds + 33280;
    float* hbuf  = lds + 33792;

    const int tid = threadIdx.x;
    const int g   = tid;
    const int row_base = blockIdx.x * 2;

    {
        const float4* src = reinterpret_cast<const float4*>(W_ih);
        float4* dst = reinterpret_cast<float4*>(wih);
        #pragma unroll
        for (int i = 0; i < 32; ++i) {
            int qq = i * 256 + tid;
            int rg = qq >> 5;
            int cc = qq & 31;
            dst[rg * 32 + (cc ^ (rg & 7))] = src[qq];
        }
    }
    float4 whh[16];
    {
        const float4* src = reinterpret_cast<const float4*>(W_hh) + g * 16;
        #pragma unroll
        for (int cc = 0; cc < 16; ++cc) whh[cc] = src[cc];
    }
    const float bias = b_ih[g] + b_hh[g];
    if (tid < 128) hbuf[tid] = 0.0f;
    {
        int r = tid >> 7, k = tid & 127;
        xbuf[tid] = x[((size_t)(row_base + r) * Tlen + 0) * Din + k];
    }
    float cstate = 0.0f, hval = 0.0f;
    __syncthreads();

    int cur = 0;
    const int sw = g & 7;
    const float4* w4 = reinterpret_cast<const float4*>(wih) + g * 32;

    for (int t = 0; t < Tlen; ++t) {
        float xnext = 0.0f;
        if (t + 1 < Tlen) {
            int r = tid >> 7, k = tid & 127;
            xnext = x[((size_t)(row_base + r) * Tlen + (t + 1)) * Din + k];
        }
        float acc0 = bias, acc1 = bias;
        {
            const float4* xr0 = reinterpret_cast<const float4*>(xbuf + cur * 256);
            const float4* xr1 = reinterpret_cast<const float4*>(xbuf + cur * 256 + 128);
            #pragma unroll 8
            for (int cc = 0; cc < 32; ++cc) {
                float4 ww = w4[cc ^ sw];
                float4 a = xr0[cc];
                float4 bb = xr1[cc];
                acc0 += ww.x * a.x + ww.y * a.y + ww.z * a.z + ww.w * a.w;
                acc1 += ww.x * bb.x + ww.y * bb.y + ww.z * bb.z + ww.w * bb.w;
            }
        }
        {
            const float4* h0 = reinterpret_cast<const float4*>(hbuf);
            const float4* h1 = reinterpret_cast<const float4*>(hbuf + 64);
            #pragma unroll
            for (int cc = 0; cc < 16; ++cc) {
                float4 ww = whh[cc];
                float4 a = h0[cc];
                float4 bb = h1[cc];
                acc0 += ww.x * a.x + ww.y * a.y + ww.z * a.z + ww.w * a.w;
                acc1 += ww.x * bb.x + ww.y * bb.y + ww.z * bb.z + ww.w * bb.w;
            }
        }
        gates[g]       = acc0;
        gates[256 + g] = acc1;
        __syncthreads();

        if (tid < 128) {
            int r = tid >> 6, jj = tid & 63;
            const float* gr = gates + r * 256;
            float ig = sigmoid_f(gr[jj]);
            float fg = sigmoid_f(gr[64 + jj]);
            float gg = tanh_f(gr[128 + jj]);
            float og = sigmoid_f(gr[192 + jj]);
            cstate = fg * cstate + ig * gg;
            hval   = og * tanh_f(cstate);
            hbuf[r * 64 + jj] = hval;
        }
        if (t + 1 < Tlen) xbuf[(cur ^ 1) * 256 + tid] = xnext;
        __syncthreads();
        cur ^= 1;
    }
    if (tid < 128) {
        int r = tid >> 6, jj = tid & 63;
        out[(size_t)(row_base + r) * Hdim + jj] = hval;
    }
}

extern "C" void kernel_launch(void* const* d_in, const int* in_sizes, int n_in,
                              void* d_out, int out_size, void* d_ws, size_t ws_size,
                              hipStream_t stream) {
    const float* x    = (const float*)d_in[0];
    const float* W_ih = (const float*)d_in[1];
    const float* W_hh = (const float*)d_in[2];
    const float* b_ih = (const float*)d_in[3];
    const float* b_hh = (const float*)d_in[4];
    float* out = (float*)d_out;

    const size_t need = (size_t)Bsz * Tlen * NGATE * 2;   // 134,217,728 B (f16 xg)
    if (ws_size >= need) {
        uint_t* xgws = (uint_t*)d_ws;
        xg_gemm2<<<512, 256, 0, stream>>>(x, W_ih, b_ih, b_hh, xgws);
        lstm_rec16<<<Bsz, 128, 0, stream>>>(xgws, W_hh, out);
    } else {
        const size_t lds_bytes = (size_t)LDS_DWORDS * 4;
        hipFuncSetAttribute(reinterpret_cast<const void*>(lstm_fused),
                            hipFuncAttributeMaxDynamicSharedMemorySize, (int)lds_bytes);
        lstm_fused<<<Bsz / 2, 256, lds_bytes, stream>>>(x, W_ih, W_hh, b_ih, b_hh, out);
    }
}

// Round 19
// 257.618 us; speedup vs baseline: 1.0668x; 1.0668x over previous
//
#include <hip/hip_runtime.h>
#include <hip/hip_fp16.h>
#include <math.h>

// LSTM: B=512, T=512, D=128, H=64. out = h_T [512,64] fp32.
// Phase 1 (xg_gemm2): xg = x@W_ih^T + b via bf16-MFMA (hi/lo x), CELL-MAJOR f16.
// Phase 2 (lstm_rec17): r17 structure (2 waves, lane = cell*2 + gate-pair,
//   DPP gate exchange) with the barrier MOVED OFF the critical path:
//   wave w owns cells [32w,32w+32); their h values are same-wave data, so the
//   K-half of the dot over own cells runs BEFORE the barrier (no sync needed),
//   and only the other wave's K-half waits. Post-barrier chain shrinks from
//   {64B read + 64 fdot2 + tail} to {32B read + 32 fdot2 + tail}. One
//   mid-step barrier, no trailing barrier; dbuf hsh keeps it race-free.

#define Bsz   512
#define Tlen  512
#define Din   128
#define Hdim  64
#define NGATE 256

typedef __attribute__((ext_vector_type(8))) short short8v;
typedef __attribute__((ext_vector_type(4))) float f32x4;
typedef __attribute__((ext_vector_type(2))) _Float16 h2v;
typedef unsigned short ushort_t;
typedef unsigned int uint_t;
typedef __attribute__((ext_vector_type(4))) uint_t uint4v;

__device__ __forceinline__ unsigned short f2bf_bits(float f) {
    union { float f; unsigned u; } v; v.f = f;
    unsigned r = v.u + 0x7fff + ((v.u >> 16) & 1);   // RNE
    return (unsigned short)(r >> 16);
}
__device__ __forceinline__ float bf2f(unsigned short b) {
    union { unsigned u; float f; } v; v.u = ((unsigned)b) << 16;
    return v.f;
}
__device__ __forceinline__ uint_t pkh(float a, float b) {   // pack 2xf16 (RNE)
    return (uint_t)__half_as_ushort(__float2half(a)) |
           ((uint_t)__half_as_ushort(__float2half(b)) << 16);
}
__device__ __forceinline__ h2v as_h2(uint_t u) {
    union { uint_t u; h2v h; } v; v.u = u; return v.h;
}
__device__ __forceinline__ float f16lo(uint_t u) {
    return __half2float(__ushort_as_half((ushort_t)(u & 0xffff)));
}
__device__ __forceinline__ float f16hi(uint_t u) {
    return __half2float(__ushort_as_half((ushort_t)(u >> 16)));
}
__device__ __forceinline__ float sigmoid_f(float v) {
    return 1.0f / (1.0f + __expf(-v));
}
__device__ __forceinline__ float tanh_f(float v) {
    float a = fabsf(v);
    float e = __expf(2.0f * a);
    float r = 1.0f - 2.0f / (e + 1.0f);
    return copysignf(r, v);
}

// DPP pair swap: lane l <-> lane l^1 within each quad (quad_perm [1,0,3,2]).
__device__ __forceinline__ float pswap(float v) {
    int r = __builtin_amdgcn_update_dpp(0, __float_as_int(v), 0xB1, 0xF, 0xF, true);
    return __int_as_float(r);
}

#if defined(__has_builtin)
#if __has_builtin(__builtin_amdgcn_fdot2)
#define FDOT2(a, b, c) __builtin_amdgcn_fdot2((a), (b), (c), false)
#endif
#endif
#ifndef FDOT2
#define FDOT2(a, b, c) fmaf((float)(a)[1], (float)(b)[1], fmaf((float)(a)[0], (float)(b)[0], (c)))
#endif

#define MF(acc, a, b) acc = __builtin_amdgcn_mfma_f32_16x16x32_bf16(a, b, acc, 0, 0, 0)

// ---------------- Phase 1: xg cell-major f16 (unchanged, ~roofline) -----------
__global__ __launch_bounds__(256, 1)
void xg_gemm2(const float* __restrict__ x, const float* __restrict__ W_ih,
              const float* __restrict__ b_ih, const float* __restrict__ b_hh,
              uint_t* __restrict__ xg)
{
    __shared__ __align__(16) ushort_t sxh[2][16][136];  // x-tile hi (pad 136)
    __shared__ __align__(16) ushort_t sxl[2][16][136];  // x-tile lo

    const int tid = threadIdx.x;
    const int l = tid & 63, q = tid >> 6;
    const int jl = l & 15, s4 = l >> 4;
    const int rb = blockIdx.x & 31, tc = blockIdx.x >> 5;
    const int t0 = tc * 32;

    short8v wb[4][4];
    #pragma unroll
    for (int tt = 0; tt < 4; ++tt) {
        #pragma unroll
        for (int kt = 0; kt < 4; ++kt) {
            const float* wp = W_ih + (size_t)(tt * 64 + q * 16 + jl) * Din + kt * 32 + s4 * 8;
            f32x4 v0 = *(const f32x4*)wp;
            f32x4 v1 = *(const f32x4*)(wp + 4);
            #pragma unroll
            for (int j = 0; j < 8; ++j)
                wb[tt][kt][j] = (short)f2bf_bits((j < 4) ? v0[j] : v1[j - 4]);
        }
    }
    float bias[4];
    #pragma unroll
    for (int tt = 0; tt < 4; ++tt) {
        int g = tt * 64 + q * 16 + jl;
        bias[tt] = b_ih[g] + b_hh[g];
    }

    const int srow = tid >> 4, spart = tid & 15;
    const float* xrow = x + (size_t)(rb * 16 + srow) * Tlen * Din + spart * 8;
    f32x4 xr0 = *(const f32x4*)(xrow + (size_t)t0 * Din);
    f32x4 xr1 = *(const f32x4*)(xrow + (size_t)t0 * Din + 4);

    for (int ti = 0; ti < 32; ++ti) {
        const int t = t0 + ti, buf = ti & 1;

        short8v vh, vl;
        #pragma unroll
        for (int j = 0; j < 8; ++j) {
            float f = (j < 4) ? xr0[j] : xr1[j - 4];
            unsigned short hb = f2bf_bits(f);
            vh[j] = (short)hb;
            vl[j] = (short)f2bf_bits(f - bf2f(hb));
        }
        *(short8v*)&sxh[buf][srow][spart * 8] = vh;
        *(short8v*)&sxl[buf][srow][spart * 8] = vl;
        __syncthreads();

        if (ti + 1 < 32) {
            xr0 = *(const f32x4*)(xrow + (size_t)(t + 1) * Din);
            xr1 = *(const f32x4*)(xrow + (size_t)(t + 1) * Din + 4);
        }

        f32x4 acc0 = {0.f, 0.f, 0.f, 0.f}, acc1 = acc0, acc2 = acc0, acc3 = acc0;
        #pragma unroll
        for (int kt = 0; kt < 4; ++kt) {
            short8v ah = *(const short8v*)&sxh[buf][jl][kt * 32 + s4 * 8];
            short8v al = *(const short8v*)&sxl[buf][jl][kt * 32 + s4 * 8];
            MF(acc0, ah, wb[0][kt]); MF(acc1, ah, wb[1][kt]);
            MF(acc2, ah, wb[2][kt]); MF(acc3, ah, wb[3][kt]);
            MF(acc0, al, wb[0][kt]); MF(acc1, al, wb[1][kt]);
            MF(acc2, al, wb[2][kt]); MF(acc3, al, wb[3][kt]);
        }

        // C layout: col(gate-sub)=jl, row(batch-sub)=s4*4+r. Cell-major store.
        #pragma unroll
        for (int r = 0; r < 4; ++r) {
            const int brow = rb * 16 + s4 * 4 + r;
            uint2 st;
            st.x = pkh(acc0[r] + bias[0], acc1[r] + bias[1]);   // i, f
            st.y = pkh(acc2[r] + bias[2], acc3[r] + bias[3]);   // g, o
            *(uint2*)(xg + ((size_t)brow * Tlen + t) * 128 + (q * 16 + jl) * 2) = st;
        }
    }
}

// ---------------- Phase 2: 2-wave split-K barrier-hiding recurrence -----------
// 512 blocks x 128 thr. Wave w: cells [32w,32w+32); lane = (c&31)*2 + p.
// p=0 -> gates {i,f}; p=1 -> {g,o}. Dot split: own-wave K-half pre-barrier,
// other-wave K-half post-barrier. W = 64 f16x2 words/lane (resident at cap).
__global__ __launch_bounds__(128) __attribute__((amdgpu_waves_per_eu(1, 1)))
void lstm_rec17(const uint_t* __restrict__ xg, const float* __restrict__ W_hh,
                float* __restrict__ out)
{
    __shared__ __align__(16) ushort_t hsh[2][Hdim];  // f16 h, double-buffered

    const int tid = threadIdx.x;
    const int l = tid & 63;
    const int w = tid >> 6;           // wave 0..1
    const int p = l & 1;              // gate pair: 0={i,f} 1={g,o}
    const int j = w * 32 + (l >> 1);  // cell 0..63
    const int b = blockIdx.x;         // batch row
    const int wown = 32 * w;          // own K-half base (cells this wave owns)
    const int woth = 32 * (1 - w);    // other wave's K-half base

    // W rows for gates (2p) and (2p+1) of cell j, split own/other K-half:
    // 4 blocks of 4 uint4v = 64 words total.
    uint4v WAo[4], WAx[4], WBo[4], WBx[4];
    {
        const float* wrA = W_hh + (size_t)((2 * p) * Hdim + j) * Hdim;
        const float* wrB = W_hh + (size_t)((2 * p + 1) * Hdim + j) * Hdim;
        const float2* ao = (const float2*)(wrA + wown);
        const float2* ax = (const float2*)(wrA + woth);
        const float2* bo = (const float2*)(wrB + wown);
        const float2* bx = (const float2*)(wrB + woth);
        #pragma unroll
        for (int qq = 0; qq < 4; ++qq) {
            #pragma unroll
            for (int cc = 0; cc < 4; ++cc) {
                float2 v;
                v = ao[qq * 4 + cc]; WAo[qq][cc] = pkh(v.x, v.y);
                v = ax[qq * 4 + cc]; WAx[qq][cc] = pkh(v.x, v.y);
                v = bo[qq * 4 + cc]; WBo[qq][cc] = pkh(v.x, v.y);
                v = bx[qq * 4 + cc]; WBx[qq][cc] = pkh(v.x, v.y);
            }
        }
    }

    if (tid < Hdim) hsh[0][tid] = 0;   // h0 = 0
    float c = 0.f, h = 0.f;
    __syncthreads();

    // cell-major xg: dword p of cell j's packet; stride/t = 128 dwords
    const uint_t* xp = xg + (size_t)b * (Tlen * 128) + j * 2 + p;

    // 4-step register batches, A/B double buffer (8 regs)
    uint_t xA[4], xB[4];
    #pragma unroll
    for (int i = 0; i < 4; ++i) xA[i] = xp[(size_t)i * 128];
    #pragma unroll
    for (int i = 0; i < 4; ++i) xB[i] = xp[(size_t)(4 + i) * 128];

#define STEP1(xv, SI) do {                                                     \
    const int buf_ = (SI) & 1;                                                 \
    /* own K-half: same-wave data (this wave wrote it) — NO barrier needed */  \
    const uint4v* hpo_ = (const uint4v*)&hsh[buf_][wown];                      \
    uint4v ho_[4];                                                             \
    _Pragma("unroll")                                                          \
    for (int i_ = 0; i_ < 4; ++i_) ho_[i_] = hpo_[i_];                         \
    float a0 = 0.f, a1 = 0.f, a2 = 0.f, a3 = 0.f;                              \
    float b0 = 0.f, b1 = 0.f, b2 = 0.f, b3 = 0.f;                              \
    _Pragma("unroll")                                                          \
    for (int q_ = 0; q_ < 4; ++q_) {                                           \
        a0 = FDOT2(as_h2(ho_[q_][0]), as_h2(WAo[q_][0]), a0);                  \
        a1 = FDOT2(as_h2(ho_[q_][1]), as_h2(WAo[q_][1]), a1);                  \
        a2 = FDOT2(as_h2(ho_[q_][2]), as_h2(WAo[q_][2]), a2);                  \
        a3 = FDOT2(as_h2(ho_[q_][3]), as_h2(WAo[q_][3]), a3);                  \
        b0 = FDOT2(as_h2(ho_[q_][0]), as_h2(WBo[q_][0]), b0);                  \
        b1 = FDOT2(as_h2(ho_[q_][1]), as_h2(WBo[q_][1]), b1);                  \
        b2 = FDOT2(as_h2(ho_[q_][2]), as_h2(WBo[q_][2]), b2);                  \
        b3 = FDOT2(as_h2(ho_[q_][3]), as_h2(WBo[q_][3]), b3);                  \
    }                                                                          \
    /* barrier guards ONLY the other wave's K-half */                          \
    __syncthreads();                                                           \
    const uint4v* hpx_ = (const uint4v*)&hsh[buf_][woth];                      \
    uint4v hx_[4];                                                             \
    _Pragma("unroll")                                                          \
    for (int i_ = 0; i_ < 4; ++i_) hx_[i_] = hpx_[i_];                         \
    _Pragma("unroll")                                                          \
    for (int q_ = 0; q_ < 4; ++q_) {                                           \
        a0 = FDOT2(as_h2(hx_[q_][0]), as_h2(WAx[q_][0]), a0);                  \
        a1 = FDOT2(as_h2(hx_[q_][1]), as_h2(WAx[q_][1]), a1);                  \
        a2 = FDOT2(as_h2(hx_[q_][2]), as_h2(WAx[q_][2]), a2);                  \
        a3 = FDOT2(as_h2(hx_[q_][3]), as_h2(WAx[q_][3]), a3);                  \
        b0 = FDOT2(as_h2(hx_[q_][0]), as_h2(WBx[q_][0]), b0);                  \
        b1 = FDOT2(as_h2(hx_[q_][1]), as_h2(WBx[q_][1]), b1);                  \
        b2 = FDOT2(as_h2(hx_[q_][2]), as_h2(WBx[q_][2]), b2);                  \
        b3 = FDOT2(as_h2(hx_[q_][3]), as_h2(WBx[q_][3]), b3);                  \
    }                                                                          \
    float preA = ((a0 + a1) + (a2 + a3)) + f16lo(xv);                          \
    float preB = ((b0 + b1) + (b2 + b3)) + f16hi(xv);                          \
    float pxA  = p ? 2.0f * preA : preA;                                       \
    float sgA  = 1.0f / (1.0f + __expf(-pxA));                                 \
    float actA = p ? 2.0f * sgA - 1.0f : sgA;                                  \
    float actB = 1.0f / (1.0f + __expf(-preB));                                \
    float oA = pswap(actA);                                                    \
    float oB = pswap(actB);                                                    \
    float iv = p ? oA   : actA;                                                \
    float fv = p ? oB   : actB;                                                \
    float gv = p ? actA : oA;                                                  \
    float ov = p ? actB : oB;                                                  \
    c = fv * c + iv * gv;                                                      \
    h = ov * tanh_f(c);                                                        \
    if (p == 0) hsh[buf_ ^ 1][j] = __half_as_ushort(__float2half(h));          \
    /* no trailing barrier: next step's own-half read is same-wave data */     \
} while (0)

#define STEP4(XARR) do {                                                       \
    _Pragma("unroll")                                                          \
    for (int si_ = 0; si_ < 4; ++si_) STEP1(XARR[si_], si_);                   \
} while (0)

    for (int bt = 0; bt < 128; bt += 2) {
        STEP4(xA);
        if (bt + 2 < 128) {
            const uint_t* rp = xp + (size_t)(bt + 2) * 4 * 128;
            #pragma unroll
            for (int i = 0; i < 4; ++i) xA[i] = rp[(size_t)i * 128];
        }
        STEP4(xB);
        if (bt + 3 < 128) {
            const uint_t* rp = xp + (size_t)(bt + 3) * 4 * 128;
            #pragma unroll
            for (int i = 0; i < 4; ++i) xB[i] = rp[(size_t)i * 128];
        }
    }
#undef STEP4
#undef STEP1

    if (p == 0) out[(size_t)b * Hdim + j] = h;
}

// ---------------- Fallback: round-1 fused kernel (proven correct) -------------
#define LDS_DWORDS 33920
__global__ void __launch_bounds__(256, 1)
lstm_fused(const float* __restrict__ x, const float* __restrict__ W_ih,
           const float* __restrict__ W_hh, const float* __restrict__ b_ih,
           const float* __restrict__ b_hh, float* __restrict__ out)
{
    extern __shared__ float lds[];
    float* wih   = lds;
    float* xbuf  = lds + 32768;
    float* gates = lds + 33280;
    float* hbuf  = lds + 33792;

    const int tid = threadIdx.x;
    const int g   = tid;
    const int row_base = blockIdx.x * 2;

    {
        const float4* src = reinterpret_cast<const float4*>(W_ih);
        float4* dst = reinterpret_cast<float4*>(wih);
        #pragma unroll
        for (int i = 0; i < 32; ++i) {
            int qq = i * 256 + tid;
            int rg = qq >> 5;
            int cc = qq & 31;
            dst[rg * 32 + (cc ^ (rg & 7))] = src[qq];
        }
    }
    float4 whh[16];
    {
        const float4* src = reinterpret_cast<const float4*>(W_hh) + g * 16;
        #pragma unroll
        for (int cc = 0; cc < 16; ++cc) whh[cc] = src[cc];
    }
    const float bias = b_ih[g] + b_hh[g];
    if (tid < 128) hbuf[tid] = 0.0f;
    {
        int r = tid >> 7, k = tid & 127;
        xbuf[tid] = x[((size_t)(row_base + r) * Tlen + 0) * Din + k];
    }
    float cstate = 0.0f, hval = 0.0f;
    __syncthreads();

    int cur = 0;
    const int sw = g & 7;
    const float4* w4 = reinterpret_cast<const float4*>(wih) + g * 32;

    for (int t = 0; t < Tlen; ++t) {
        float xnext = 0.0f;
        if (t + 1 < Tlen) {
            int r = tid >> 7, k = tid & 127;
            xnext = x[((size_t)(row_base + r) * Tlen + (t + 1)) * Din + k];
        }
        float acc0 = bias, acc1 = bias;
        {
            const float4* xr0 = reinterpret_cast<const float4*>(xbuf + cur * 256);
            const float4* xr1 = reinterpret_cast<const float4*>(xbuf + cur * 256 + 128);
            #pragma unroll 8
            for (int cc = 0; cc < 32; ++cc) {
                float4 ww = w4[cc ^ sw];
                float4 a = xr0[cc];
                float4 bb = xr1[cc];
                acc0 += ww.x * a.x + ww.y * a.y + ww.z * a.z + ww.w * a.w;
                acc1 += ww.x * bb.x + ww.y * bb.y + ww.z * bb.z + ww.w * bb.w;
            }
        }
        {
            const float4* h0 = reinterpret_cast<const float4*>(hbuf);
            const float4* h1 = reinterpret_cast<const float4*>(hbuf + 64);
            #pragma unroll
            for (int cc = 0; cc < 16; ++cc) {
                float4 ww = whh[cc];
                float4 a = h0[cc];
                float4 bb = h1[cc];
                acc0 += ww.x * a.x + ww.y * a.y + ww.z * a.z + ww.w * a.w;
                acc1 += ww.x * bb.x + ww.y * bb.y + ww.z * bb.z + ww.w * bb.w;
            }
        }
        gates[g]       = acc0;
        gates[256 + g] = acc1;
        __syncthreads();

        if (tid < 128) {
            int r = tid >> 6, jj = tid & 63;
            const float* gr = gates + r * 256;
            float ig = sigmoid_f(gr[jj]);
            float fg = sigmoid_f(gr[64 + jj]);
            float gg = tanh_f(gr[128 + jj]);
            float og = sigmoid_f(gr[192 + jj]);
            cstate = fg * cstate + ig * gg;
            hval   = og * tanh_f(cstate);
            hbuf[r * 64 + jj] = hval;
        }
        if (t + 1 < Tlen) xbuf[(cur ^ 1) * 256 + tid] = xnext;
        __syncthreads();
        cur ^= 1;
    }
    if (tid < 128) {
        int r = tid >> 6, jj = tid & 63;
        out[(size_t)(row_base + r) * Hdim + jj] = hval;
    }
}

extern "C" void kernel_launch(void* const* d_in, const int* in_sizes, int n_in,
                              void* d_out, int out_size, void* d_ws, size_t ws_size,
                              hipStream_t stream) {
    const float* x    = (const float*)d_in[0];
    const float* W_ih = (const float*)d_in[1];
    const float* W_hh = (const float*)d_in[2];
    const float* b_ih = (const float*)d_in[3];
    const float* b_hh = (const float*)d_in[4];
    float* out = (float*)d_out;

    const size_t need = (size_t)Bsz * Tlen * NGATE * 2;   // 134,217,728 B (f16 xg)
    if (ws_size >= need) {
        uint_t* xgws = (uint_t*)d_ws;
        xg_gemm2<<<512, 256, 0, stream>>>(x, W_ih, b_ih, b_hh, xgws);
        lstm_rec17<<<Bsz, 128, 0, stream>>>(xgws, W_hh, out);
    } else {
        const size_t lds_bytes = (size_t)LDS_DWORDS * 4;
        hipFuncSetAttribute(reinterpret_cast<const void*>(lstm_fused),
                            hipFuncAttributeMaxDynamicSharedMemorySize, (int)lds_bytes);
        lstm_fused<<<Bsz / 2, 256, lds_bytes, stream>>>(x, W_ih, W_hh, b_ih, b_hh, out);
    }
}